// Round 11
// baseline (263.928 us; speedup 1.0000x reference)
//
#include <hip/hip_runtime.h>
#include <hip/hip_cooperative_groups.h>
#include <math.h>

namespace cg = cooperative_groups;

#define SDIM 376
#define ADIM 17
#define DIN  393
#define H1   400
#define H2   300
#define TSTEPS 32
#define KP 416   // 13*32
#define NKT 13   // K tiles of 32

typedef __bf16 bf16x8 __attribute__((ext_vector_type(8)));
typedef float  f32x4  __attribute__((ext_vector_type(4)));

// ---------------- shared phase bodies (used by both coop and fallback paths) ----------------
// Fragment-major layouts:
//   A_sw[((mtile*13 + kt)*64 + lane)*8 + e]   lane = quad*16 + (row&15)
//   B_sw[((ntile*13 + kt)*64 + lane)*8 + e]   lane = quad*16 + (col&15)
// => every MFMA fragment load is ONE coalesced 1KB wave transaction.

__device__ __forceinline__ void phase_pack_unit(
    int bid, int tid, const float* __restrict__ state, const float* __restrict__ action,
    const float* __restrict__ W1, __bf16* __restrict__ A_sw, __bf16* __restrict__ B_sw,
    int B, int npack) {
    if (bid < npack) {
        int idx = bid * 256 + tid;
        int r = idx / 52, c = idx - r * 52;
        if (r >= B) return;
        int g0 = c * 8;
        float v[8];
        if (g0 + 7 < SDIM) {
            float4 a = *(const float4*)&state[r * SDIM + g0];
            float4 bb = *(const float4*)&state[r * SDIM + g0 + 4];
            v[0]=a.x; v[1]=a.y; v[2]=a.z; v[3]=a.w; v[4]=bb.x; v[5]=bb.y; v[6]=bb.z; v[7]=bb.w;
        } else {
            #pragma unroll
            for (int e = 0; e < 8; ++e) {
                int k = g0 + e;
                v[e] = (k < SDIM) ? state[r * SDIM + k]
                     : (k < DIN)  ? action[r * ADIM + k - SDIM] : 0.f;
            }
        }
        bf16x8 o;
        #pragma unroll
        for (int e = 0; e < 8; ++e) o[e] = (__bf16)v[e];
        int kt = g0 >> 5, quad = (g0 >> 3) & 3;
        *(bf16x8*)&A_sw[(((size_t)(r >> 4) * NKT + kt) * 64 + (quad << 4) + (r & 15)) * 8] = o;
    } else {
        int idx = (bid - npack) * 256 + tid;
        if (idx >= H1 * KP) return;
        int k = idx / H1, n = idx - k * H1;
        float val = (k < DIN) ? W1[k * H1 + n] : 0.f;
        int ntile = n >> 4, kt = k >> 5, quad = (k >> 3) & 3;
        B_sw[(((size_t)ntile * NKT + kt) * 64 + (quad << 4) + (n & 15)) * 8 + (k & 7)] = (__bf16)val;
    }
}

__device__ __forceinline__ void phase_gemm_unit(
    int bx, int by, int tid, const __bf16* __restrict__ A_sw, const __bf16* __restrict__ B_sw,
    const float* __restrict__ b1, unsigned short* __restrict__ maskbuf) {
    const int wave = tid >> 6, lane = tid & 63;
    const int quad = lane >> 4, l16 = lane & 15;
    const int mtile = bx * 4 + wave;
    const int bn0 = by * 80;

    f32x4 acc[5];
    #pragma unroll
    for (int n = 0; n < 5; ++n) acc[n] = (f32x4){0.f, 0.f, 0.f, 0.f};

    const __bf16* ap = A_sw + ((size_t)mtile * NKT * 64 + lane) * 8;
    const __bf16* bp = B_sw + ((size_t)(by * 5) * NKT * 64 + lane) * 8;

    #pragma unroll
    for (int kt = 0; kt < NKT; ++kt) {
        bf16x8 af = *(const bf16x8*)(ap + (size_t)kt * 512);
        #pragma unroll
        for (int n = 0; n < 5; ++n) {
            bf16x8 bfrag = *(const bf16x8*)(bp + ((size_t)n * NKT + kt) * 512);
            acc[n] = __builtin_amdgcn_mfma_f32_16x16x32_bf16(af, bfrag, acc[n], 0, 0, 0);
        }
    }
    float b1v[5];
    #pragma unroll
    for (int n = 0; n < 5; ++n) b1v[n] = b1[bn0 + n * 16 + l16];
    const int cbase = by * 5;
    const int bm0 = mtile * 16;
    #pragma unroll
    for (int n = 0; n < 5; ++n)
        #pragma unroll
        for (int reg = 0; reg < 4; ++reg) {
            // 0.99: superset of {x1_ref >= 1}; bf16 GEMM |err| << 0.01 at this K/scale
            unsigned long long bal = __ballot(acc[n][reg] + b1v[n] >= 0.99f);
            if (l16 == 0)
                maskbuf[(size_t)(bm0 + quad * 4 + reg) * 32 + cbase + n] =
                    (unsigned short)(bal >> (quad * 16));
        }
}

__device__ __forceinline__ void phase_snn_row(
    int row, int lane, const unsigned long long* __restrict__ mask64,
    const float* __restrict__ state, const float* __restrict__ action,
    const float* __restrict__ W1, const float* __restrict__ b1,
    const float* __restrict__ W2, const float* __restrict__ b2,
    const float* __restrict__ W3, const float* __restrict__ b3,
    float* __restrict__ out) {
    unsigned long long mw = 0;
    if (lane < 7) {
        mw = mask64[row * 8 + lane];
        if (lane == 6) mw &= 0xFFFFULL;  // chunks 25..27 are unwritten ws
    }
    const float act = (lane < ADIM) ? action[row * ADIM + lane] : 0.f;
    const float b3v = (lane < ADIM) ? b3[lane] : 0.f;

    // closed-form if s2==0: v3 charges toward b3; g = 0.05*tanh(max_t v3_t)
    float v3c = 0.f, vmc = -3.0e38f;
    #pragma unroll
    for (int t = 0; t < TSTEPS; ++t) { v3c += (b3v - v3c) * 0.5f; vmc = fmaxf(vmc, v3c); }
    const float gv = 0.05f * tanhf(vmc);

    // exact bound: b2[j] + sum_{i in mask} max(W2[i][j],0) < 0.999 for all j
    float bound[5];
    #pragma unroll
    for (int c = 0; c < 5; ++c) { int j = lane + 64 * c; bound[c] = (j < H2) ? b2[j] : 0.f; }
    #pragma unroll 1
    for (int w = 0; w < 7; ++w) {
        unsigned long long m = __shfl(mw, w);
        while (m) {
            int c0 = __builtin_ctzll(m); m &= m - 1;
            const float* r0 = W2 + (w * 64 + c0) * H2;
            if (m) {
                int c1 = __builtin_ctzll(m); m &= m - 1;
                const float* r1 = W2 + (w * 64 + c1) * H2;
                float t0[5], t1[5];
                #pragma unroll
                for (int c = 0; c < 5; ++c) {
                    int j = lane + 64 * c;
                    t0[c] = (j < H2) ? r0[j] : 0.f;
                    t1[c] = (j < H2) ? r1[j] : 0.f;
                }
                #pragma unroll
                for (int c = 0; c < 5; ++c) bound[c] += fmaxf(t0[c], 0.f) + fmaxf(t1[c], 0.f);
            } else {
                #pragma unroll
                for (int c = 0; c < 5; ++c) {
                    int j = lane + 64 * c;
                    bound[c] += (j < H2) ? fmaxf(r0[j], 0.f) : 0.f;
                }
            }
        }
    }
    bool okb = true;
    #pragma unroll
    for (int c = 0; c < 5; ++c) okb = okb && (bound[c] < 0.999f);
    if (__all(okb)) {
        if (lane < ADIM) out[row * ADIM + lane] = fminf(fmaxf(gv + act, -1.f), 1.f);
        return;
    }

    // tier3 soundness net (never taken in practice): f32 x1 + full sim
    float x1v[7];
    #pragma unroll
    for (int s = 0; s < 7; ++s) { int col = lane + 64 * s; x1v[s] = (col < H1) ? b1[col] : 0.f; }
    for (int k = 0; k < DIN; ++k) {
        float ik = (k < SDIM) ? state[row * SDIM + k] : action[row * ADIM + k - SDIM];
        #pragma unroll
        for (int s = 0; s < 7; ++s) {
            int col = lane + 64 * s;
            if (col < H1) x1v[s] += ik * W1[k * H1 + col];
        }
    }
    float b2v[5];
    #pragma unroll
    for (int c = 0; c < 5; ++c) { int j = lane + 64 * c; b2v[c] = (j < H2) ? b2[j] : 0.f; }
    float v1[7], v2[5], v3 = 0.f, vmax = -3.0e38f;
    #pragma unroll
    for (int s = 0; s < 7; ++s) v1[s] = 0.f;
    #pragma unroll
    for (int c = 0; c < 5; ++c) v2[c] = 0.f;
    for (int t = 0; t < TSTEPS; ++t) {
        float x2[5];
        #pragma unroll
        for (int c = 0; c < 5; ++c) x2[c] = b2v[c];
        #pragma unroll
        for (int s = 0; s < 7; ++s) {
            float v = v1[s] + (x1v[s] - v1[s]) * 0.5f;
            bool sp = v >= 1.0f;
            v1[s] = sp ? 0.f : v;
            unsigned long long m = __ballot(sp);
            while (m) {
                int j = __builtin_ctzll(m); m &= m - 1;
                const float* wr = W2 + (s * 64 + j) * H2;
                #pragma unroll
                for (int c = 0; c < 5; ++c) {
                    int col = lane + 64 * c;
                    if (col < H2) x2[c] += wr[col];
                }
            }
        }
        float x3 = b3v;
        #pragma unroll
        for (int c = 0; c < 5; ++c) {
            float v = v2[c] + (x2[c] - v2[c]) * 0.5f;
            int col = lane + 64 * c;
            bool sp = (col < H2) && (v >= 1.0f);
            v2[c] = sp ? 0.f : v;
            unsigned long long m = __ballot(sp);
            while (m) {
                int j = __builtin_ctzll(m); m &= m - 1;
                if (lane < ADIM) x3 += W3[(c * 64 + j) * ADIM + lane];
            }
        }
        v3 += (x3 - v3) * 0.5f;
        vmax = fmaxf(vmax, v3);
    }
    if (lane < ADIM)
        out[row * ADIM + lane] = fminf(fmaxf(0.05f * tanhf(vmax) + act, -1.f), 1.f);
}

// ---------------- single cooperative kernel (primary path) ----------------
__global__ __launch_bounds__(256) void actor_fused(
    const float* __restrict__ state, const float* __restrict__ action,
    const float* __restrict__ W1, const float* __restrict__ b1,
    const float* __restrict__ W2, const float* __restrict__ b2,
    const float* __restrict__ W3, const float* __restrict__ b3,
    __bf16* __restrict__ A_sw, __bf16* __restrict__ B_sw,
    unsigned short* __restrict__ maskbuf, float* __restrict__ out, int B) {
    cg::grid_group grid = cg::this_grid();
    const int tid = threadIdx.x;
    const int nb = gridDim.x;
    const int npack = (B * 52 + 255) / 256;
    const int nw1t  = (H1 * KP + 255) / 256;

    for (int bid = blockIdx.x; bid < npack + nw1t; bid += nb)
        phase_pack_unit(bid, tid, state, action, W1, A_sw, B_sw, B, npack);
    grid.sync();

    const int nbx = B / 64;
    for (int unit = blockIdx.x; unit < nbx * 5; unit += nb)
        phase_gemm_unit(unit % nbx, unit / nbx, tid, A_sw, B_sw, b1, maskbuf);
    grid.sync();

    const unsigned long long* mask64 = (const unsigned long long*)maskbuf;
    const int lane = tid & 63;
    for (int unit = blockIdx.x; unit < B / 4; unit += nb)
        phase_snn_row(unit * 4 + (tid >> 6), lane, mask64, state, action,
                      W1, b1, W2, b2, W3, b3, out);
}

// ---------------- fallback 3-kernel path (proven R9 structure) ----------------
__global__ __launch_bounds__(256) void prep_k(
    const float* __restrict__ state, const float* __restrict__ action,
    const float* __restrict__ W1, __bf16* __restrict__ A_sw, __bf16* __restrict__ B_sw,
    int B, int npack) {
    phase_pack_unit(blockIdx.x, threadIdx.x, state, action, W1, A_sw, B_sw, B, npack);
}

__global__ __launch_bounds__(256) void gemm_k(
    const __bf16* __restrict__ A_sw, const __bf16* __restrict__ B_sw,
    const float* __restrict__ b1, unsigned short* __restrict__ maskbuf) {
    phase_gemm_unit(blockIdx.x, blockIdx.y, threadIdx.x, A_sw, B_sw, b1, maskbuf);
}

__global__ __launch_bounds__(256) void snn_k(
    const unsigned long long* __restrict__ mask64,
    const float* __restrict__ state, const float* __restrict__ action,
    const float* __restrict__ W1, const float* __restrict__ b1,
    const float* __restrict__ W2, const float* __restrict__ b2,
    const float* __restrict__ W3, const float* __restrict__ b3,
    float* __restrict__ out) {
    phase_snn_row(blockIdx.x * 4 + (threadIdx.x >> 6), threadIdx.x & 63, mask64,
                  state, action, W1, b1, W2, b2, W3, b3, out);
}

extern "C" void kernel_launch(void* const* d_in, const int* in_sizes, int n_in,
                              void* d_out, int out_size, void* d_ws, size_t ws_size,
                              hipStream_t stream) {
    const float* state  = (const float*)d_in[0];
    const float* action = (const float*)d_in[1];
    const float* W1     = (const float*)d_in[2];
    const float* b1     = (const float*)d_in[3];
    const float* W2     = (const float*)d_in[4];
    const float* b2     = (const float*)d_in[5];
    const float* W3     = (const float*)d_in[6];
    const float* b3     = (const float*)d_in[7];
    float* out = (float*)d_out;

    int B = in_sizes[0] / SDIM;  // 8192

    char* p = (char*)d_ws;
    __bf16* A_sw = (__bf16*)p;                 p += (size_t)B * KP * 2;
    __bf16* B_sw = (__bf16*)p;                 p += (size_t)H1 * KP * 2;
    unsigned short* maskbuf = (unsigned short*)p;
    const int npack = (B * 52 + 255) / 256;        // 1664
    const int nw1t  = (H1 * KP + 255) / 256;       // 650

    // Size the cooperative grid from real occupancy (host-side query, capture-safe).
    int occ = 0;
    hipError_t qe = hipOccupancyMaxActiveBlocksPerMultiprocessor(&occ, actor_fused, 256, 0);
    int numCU = 256;
    int dev = 0;
    if (hipGetDevice(&dev) == hipSuccess)
        hipDeviceGetAttribute(&numCU, hipDeviceAttributeMultiprocessorCount, dev);

    bool coop_ok = (qe == hipSuccess) && (occ >= 1);
    if (coop_ok) {
        int grid = occ * numCU;
        if (grid > 2048) grid = 2048;
        void* kargs[] = {&state, &action, &W1, &b1, &W2, &b2, &W3, &b3,
                         &A_sw, &B_sw, &maskbuf, &out, &B};
        hipError_t le = hipLaunchCooperativeKernel((const void*)actor_fused, dim3(grid),
                                                   dim3(256), kargs, 0, stream);
        if (le == hipSuccess) return;
    }
    // Deterministic fallback: proven 3-kernel path
    prep_k<<<npack + nw1t, 256, 0, stream>>>(state, action, W1, A_sw, B_sw, B, npack);
    gemm_k<<<dim3(B / 64, 5), 256, 0, stream>>>(A_sw, B_sw, b1, maskbuf);
    snn_k<<<B / 4, 256, 0, stream>>>((const unsigned long long*)maskbuf, state, action,
                                     W1, b1, W2, b2, W3, b3, out);
}